// Round 3
// baseline (107.101 us; speedup 1.0000x reference)
//
#include <hip/hip_runtime.h>

// AGMBrain: N=128, B=32, IN_FEAT=4608, grid_size=3, num_candidates=8, n_steps=2
//
// Algebraic reduction (verified rounds 1-2):
//   messages[b,d,i] = (sum_j T[b,d,i,j]) * (sum_n s[b,d,n])   (einsum factorizes)
//   Step 1 closed form: m1[b,d,i] = (colsum[d] + 128 t) * (At[d,i] + t*e[i]),
//     t = x_t[b,d], At[d,i] = sum_n EJ[i,n] NS[n,d], EJ[i,n] = sum_j E[i,j,n],
//     e[i] = sum_n EJ[i,n]
//   Step 2 only needs i = 127: out[b,d] = relu((d!=127) * sig * (EJ[127,:]·s1))
//
// Round 3: 4 kernels -> 3 (K2+K3 fused per-d); x_t 2x2 register tiling.
// Note: measured dur_us includes ~85 us of harness reset (268 MB ws 0xAA fill
// = 41.5 us + ~12 serialized d_in restore ops) — only ~40 us was ours.

#define KQ 1152  // 4608/4

__device__ __forceinline__ float wave_reduce64(float v) {
#pragma unroll
  for (int m = 32; m >= 1; m >>= 1) v += __shfl_xor(v, m);
  return v;
}

// ws float offsets
#define WS_EJP 0      // 4*128*128 = 65536 (EJ partials [jc][i][n])
#define WS_XT 65536   // 4096
#define WS_OBD 69632  // 4096
// total 73728 floats = 295 KB

// K1: blocks 0..511 -> EJ partials (blk = i*4+jc, sum 32 j's)
//     blocks 512..767 -> x_t, one wave per 2b x 2d tile
__global__ __launch_bounds__(256) void k1_pre(const float* __restrict__ ev,
                                              const float* __restrict__ x,
                                              const float* __restrict__ ipw,
                                              const float* __restrict__ ipb,
                                              float* __restrict__ ws) {
  int tid = threadIdx.x, blk = blockIdx.x;
  if (blk < 512) {
    __shared__ __align__(16) float4 sarr[256];
    int i = blk >> 2, jc = blk & 3;
    int n4 = tid & 31, jg = tid >> 5;  // 8 j-groups
    const float4* ev4 = (const float4*)ev;
    float4 acc = make_float4(0.f, 0.f, 0.f, 0.f);
#pragma unroll
    for (int jj = 0; jj < 4; ++jj) {
      int j = jc * 32 + jj * 8 + jg;
      float4 v = ev4[i * 4096 + j * 32 + n4];
      acc.x += v.x; acc.y += v.y; acc.z += v.z; acc.w += v.w;
    }
    sarr[tid] = acc;
    __syncthreads();
    if (tid < 32) {
      float4 s = sarr[tid];
#pragma unroll
      for (int k = 1; k < 8; ++k) {
        float4 v = sarr[tid + 32 * k];
        s.x += v.x; s.y += v.y; s.z += v.z; s.w += v.w;
      }
      ((float4*)(ws + WS_EJP))[(jc * 128 + i) * 32 + tid] = s;
    }
  } else {
    int gw = (blk - 512) * 4 + (tid >> 6);  // 0..1023
    int lane = tid & 63;
    int b0 = (gw >> 6) << 1, d0 = (gw & 63) << 1;
    const float4* x4 = (const float4*)x;
    const float4* w4 = (const float4*)ipw;
    float a00 = 0.f, a01 = 0.f, a10 = 0.f, a11 = 0.f;
#pragma unroll 6
    for (int kq = lane; kq < KQ; kq += 64) {
      float4 xa = x4[b0 * KQ + kq];
      float4 xb = x4[(b0 + 1) * KQ + kq];
      float4 wa = w4[d0 * KQ + kq];
      float4 wb = w4[(d0 + 1) * KQ + kq];
      a00 += xa.x * wa.x + xa.y * wa.y + xa.z * wa.z + xa.w * wa.w;
      a01 += xa.x * wb.x + xa.y * wb.y + xa.z * wb.z + xa.w * wb.w;
      a10 += xb.x * wa.x + xb.y * wa.y + xb.z * wa.z + xb.w * wa.w;
      a11 += xb.x * wb.x + xb.y * wb.y + xb.z * wb.z + xb.w * wb.w;
    }
    a00 = wave_reduce64(a00);
    a01 = wave_reduce64(a01);
    a10 = wave_reduce64(a10);
    a11 = wave_reduce64(a11);
    if (lane == 0) {
      float* xt = ws + WS_XT;
      xt[b0 * 128 + d0] = a00 + ipb[d0];
      xt[b0 * 128 + d0 + 1] = a01 + ipb[d0 + 1];
      xt[(b0 + 1) * 128 + d0] = a10 + ipb[d0];
      xt[(b0 + 1) * 128 + d0 + 1] = a11 + ipb[d0 + 1];
    }
  }
}

// K2 fused: one block per d. Reduce EJ partials into LDS (stride 129:
// conflict-free), compute At[d,:], e, colsum, then step1+step2 for all 32 b.
#define EJS 129
__global__ __launch_bounds__(256) void k2_fused(const float* __restrict__ ns,
                                                float* __restrict__ ws) {
  __shared__ float ej[128 * EJS];
  __shared__ float nscol[128];
  __shared__ float at2[2][128], e2[2][128];
  __shared__ float At[128], Ev[128];
  __shared__ float xts[32];
  __shared__ float csum_s;
  int tid = threadIdx.x, d = blockIdx.x;
  if (tid < 128) nscol[tid] = ns[tid * 128 + d];
  else if (tid < 160) xts[tid - 128] = (ws + WS_XT)[(tid - 128) * 128 + d];
  {
    // thread -> (i = tid>>1, half = tid&1): reduce 4 partial planes into ej
    int i = tid >> 1, h = tid & 1;
    const float4* p0 = (const float4*)(ws + WS_EJP) + i * 32 + h * 16;
#pragma unroll
    for (int w = 0; w < 16; ++w) {
      float4 v0 = p0[w];
      float4 v1 = p0[4096 + w];
      float4 v2 = p0[8192 + w];
      float4 v3 = p0[12288 + w];
      float* dst = &ej[i * EJS + h * 64 + w * 4];
      dst[0] = v0.x + v1.x + v2.x + v3.x;
      dst[1] = v0.y + v1.y + v2.y + v3.y;
      dst[2] = v0.z + v1.z + v2.z + v3.z;
      dst[3] = v0.w + v1.w + v2.w + v3.w;
    }
  }
  __syncthreads();
  {
    // At[d,i] and e[i], split n-range over 2 halves
    int i = tid & 127, h = tid >> 7;
    float a = 0.f, es = 0.f;
    const float* ejr = &ej[i * EJS + h * 64];
    const float* nsr = &nscol[h * 64];
#pragma unroll 8
    for (int n = 0; n < 64; ++n) {
      float v = ejr[n];
      a += v * nsr[n];
      es += v;
    }
    at2[h][i] = a;
    e2[h][i] = es;
  }
  if (tid < 64) {
    float cl = nscol[tid] + nscol[tid + 64];
    cl = wave_reduce64(cl);
    if (tid == 0) csum_s = cl;
  }
  __syncthreads();
  if (tid < 128) {
    At[tid] = at2[0][tid] + at2[1][tid];
    Ev[tid] = e2[0][tid] + e2[1][tid];
  }
  __syncthreads();
  float csum = csum_s;
  int wv = tid >> 6, l = tid & 63;
  const float* ej127 = &ej[127 * EJS];
  float* obd = ws + WS_OBD;
#pragma unroll
  for (int bb = 0; bb < 8; ++bb) {
    int b = wv * 8 + bb;
    float t = xts[b];
    float s0s = csum + 128.f * t;
    float sig = 0.f, y = 0.f;
#pragma unroll
    for (int m = 0; m < 2; ++m) {
      int i = l + (m << 6);
      float v = s0s * (At[i] + t * Ev[i]);
      v = (i == d) ? 0.f : v;  // step-1 mask
      v = fmaxf(v, 0.f);       // relu
      sig += v;
      y += ej127[i] * v;
    }
    sig = wave_reduce64(sig);
    y = wave_reduce64(y);
    if (l == 0) {
      float m2 = sig * y;
      if (d == 127) m2 = 0.f;  // step-2 mask (i=127)
      obd[b * 128 + d] = fmaxf(m2, 0.f);
    }
  }
}

// K3: blocks 0..143: recreation tile 32 f x 32 b; block 144: scores
__global__ __launch_bounds__(256) void k3_proj(const float* __restrict__ rw,
                                               const float* __restrict__ rb,
                                               const float* __restrict__ sw,
                                               const float* __restrict__ sb,
                                               const float* __restrict__ ws,
                                               float* __restrict__ out) {
  const float* obd = ws + WS_OBD;
  int tid = threadIdx.x;
  int blk = blockIdx.x;
  if (blk < 144) {
    __shared__ __align__(16) float rwlds[32 * 136];
    __shared__ float obdT[128 * 33];
    int f0 = blk * 32;
    const float4* rw4 = (const float4*)rw;
#pragma unroll
    for (int it = 0; it < 4; ++it) {
      int q = tid + 256 * it;
      int f = q >> 5, n4 = q & 31;
      *(float4*)&rwlds[f * 136 + n4 * 4] = rw4[f0 * 32 + q];
    }
#pragma unroll
    for (int it = 0; it < 16; ++it) {
      int q = tid + 256 * it;
      int b = q >> 7, d = q & 127;
      obdT[d * 33 + b] = obd[q];
    }
    __syncthreads();
    int f = tid >> 3, bg = tid & 7;
    float acc[4] = {0.f, 0.f, 0.f, 0.f};
#pragma unroll 4
    for (int d = 0; d < 128; ++d) {
      float w = rwlds[f * 136 + d];
#pragma unroll
      for (int k = 0; k < 4; ++k) acc[k] += w * obdT[d * 33 + bg * 4 + k];
    }
    float bias = rb[f0 + f];
#pragma unroll
    for (int k = 0; k < 4; ++k) out[(bg * 4 + k) * 4608 + f0 + f] = acc[k] + bias;
  } else {
    int b = tid >> 3, l8 = tid & 7;
    float acc = 0.f;
    for (int d = l8; d < 128; d += 8) acc += obd[b * 128 + d] * sw[d];
    acc += __shfl_xor(acc, 1);
    acc += __shfl_xor(acc, 2);
    acc += __shfl_xor(acc, 4);
    if (l8 == 0) out[147456 + b] = acc + sb[0];
  }
}

extern "C" void kernel_launch(void* const* d_in, const int* in_sizes, int n_in,
                              void* d_out, int out_size, void* d_ws, size_t ws_size,
                              hipStream_t stream) {
  const float* x   = (const float*)d_in[0];   // (32, 4608)
  const float* ipw = (const float*)d_in[1];   // (128, 4608)
  const float* ipb = (const float*)d_in[2];   // (128,)
  const float* ns  = (const float*)d_in[3];   // (128, 128)
  const float* ev  = (const float*)d_in[4];   // (128, 128, 128)
  const float* rw  = (const float*)d_in[5];   // (4608, 128)
  const float* rb  = (const float*)d_in[6];   // (4608,)
  const float* sw  = (const float*)d_in[7];   // (1, 128)
  const float* sb  = (const float*)d_in[8];   // (1,)
  float* out = (float*)d_out;                 // 147456 recreation + 32 scores
  float* ws = (float*)d_ws;                   // needs >= 73728 floats (~295 KB)

  k1_pre<<<768, 256, 0, stream>>>(ev, x, ipw, ipb, ws);
  k2_fused<<<128, 256, 0, stream>>>(ns, ws);
  k3_proj<<<145, 256, 0, stream>>>(rw, rb, sw, sb, ws, out);
}

// Round 4
// 99.230 us; speedup vs baseline: 1.0793x; 1.0793x over previous
//
#include <hip/hip_runtime.h>

// AGMBrain: N=128, B=32, IN_FEAT=4608, grid_size=3, num_candidates=8, n_steps=2
//
// Algebraic reduction (verified rounds 1-3):
//   einsum 'bdij,bdn->bdi' factorizes: messages[b,d,i] =
//     (sum_j T[b,d,i,j]) * (sum_n s[b,d,n])
//   Step 1 closed form: m1[b,d,i] = (colsum[d] + 128 t) * (At[d,i] + t*e[i]),
//     t = x_t[b,d], At[d,i] = sum_n EJ[i,n] NS[n,d], EJ[i,n] = sum_j ev[i,j,n],
//     e[i] = sum_n EJ[i,n]
//   Step 2 only needs i = 127: out[b,d] = relu((d!=127) * sig * (EJ[127,:]·s1))
//
// Round 4: lean 3-kernel pipeline. K1 finalizes EJ (transposed EJT + e + row127),
// K2 is per-d with 2 KB LDS and register-resident step phase, K3 unchanged.
// Measured floor note: ~85-95 us of every timed iteration is harness reset
// (268 MB d_ws 0xAA fill ~43 us + dozens of restore dispatches).

#define KQ 1152  // 4608/4

__device__ __forceinline__ float wave_reduce64(float v) {
#pragma unroll
  for (int m = 32; m >= 1; m >>= 1) v += __shfl_xor(v, m);
  return v;
}
__device__ __forceinline__ float wave_reduce32(float v) {
#pragma unroll
  for (int m = 16; m >= 1; m >>= 1) v += __shfl_xor(v, m);
  return v;
}

// ws float offsets
#define WS_EJT 0       // 16384: EJT[n*128 + i] = EJ[i,n]
#define WS_E 16384     // 128:   e[i]
#define WS_EJ127 16512 // 128:   EJ[127, :]
#define WS_XT 16640    // 4096:  x_t[b*128 + d]
#define WS_OBD 20736   // 4096:  out[b*128 + d]
// total 24832 floats = 99 KB

// K1: blocks 0..127  -> EJ row i: 16 indep float4 loads/thread, LDS reduce,
//                       write EJT column + e[i] (+ EJ127 row for i==127)
//     blocks 128..383 -> x_t, one wave per 2b x 2d tile
__global__ __launch_bounds__(256) void k1_pre(const float* __restrict__ ev,
                                              const float* __restrict__ x,
                                              const float* __restrict__ ipw,
                                              const float* __restrict__ ipb,
                                              float* __restrict__ ws) {
  int tid = threadIdx.x, blk = blockIdx.x;
  if (blk < 128) {
    __shared__ __align__(16) float4 sarr[256];
    int i = blk;
    int n4 = tid & 31, jg = tid >> 5;  // 8 j-groups x 16 j each
    const float4* ev4 = (const float4*)ev;
    float4 acc = make_float4(0.f, 0.f, 0.f, 0.f);
#pragma unroll
    for (int jj = 0; jj < 16; ++jj) {
      int j = jg * 16 + jj;
      float4 v = ev4[i * 4096 + j * 32 + n4];
      acc.x += v.x; acc.y += v.y; acc.z += v.z; acc.w += v.w;
    }
    sarr[tid] = acc;
    __syncthreads();
    if (tid < 32) {
      float4 s = sarr[tid];
#pragma unroll
      for (int k = 1; k < 8; ++k) {
        float4 v = sarr[tid + 32 * k];
        s.x += v.x; s.y += v.y; s.z += v.z; s.w += v.w;
      }
      // EJT column i (scatter, 4 dwords): EJT[n*128 + i] = EJ[i,n]
      float* EJT = ws + WS_EJT;
      int n0 = tid * 4;
      EJT[(n0 + 0) * 128 + i] = s.x;
      EJT[(n0 + 1) * 128 + i] = s.y;
      EJT[(n0 + 2) * 128 + i] = s.z;
      EJT[(n0 + 3) * 128 + i] = s.w;
      if (i == 127) *(float4*)(ws + WS_EJ127 + n0) = s;
      float p = s.x + s.y + s.z + s.w;
      p = wave_reduce32(p);
      if (tid == 0) (ws + WS_E)[i] = p;
    }
  } else {
    int gw = (blk - 128) * 4 + (tid >> 6);  // 0..1023 tiles
    int lane = tid & 63;
    int b0 = (gw >> 6) << 1, d0 = (gw & 63) << 1;
    const float4* x4 = (const float4*)x;
    const float4* w4 = (const float4*)ipw;
    float a00 = 0.f, a01 = 0.f, a10 = 0.f, a11 = 0.f;
#pragma unroll 6
    for (int kq = lane; kq < KQ; kq += 64) {
      float4 xa = x4[b0 * KQ + kq];
      float4 xb = x4[(b0 + 1) * KQ + kq];
      float4 wa = w4[d0 * KQ + kq];
      float4 wb = w4[(d0 + 1) * KQ + kq];
      a00 += xa.x * wa.x + xa.y * wa.y + xa.z * wa.z + xa.w * wa.w;
      a01 += xa.x * wb.x + xa.y * wb.y + xa.z * wb.z + xa.w * wb.w;
      a10 += xb.x * wa.x + xb.y * wa.y + xb.z * wa.z + xb.w * wa.w;
      a11 += xb.x * wb.x + xb.y * wb.y + xb.z * wb.z + xb.w * wb.w;
    }
    a00 = wave_reduce64(a00);
    a01 = wave_reduce64(a01);
    a10 = wave_reduce64(a10);
    a11 = wave_reduce64(a11);
    if (lane == 0) {
      float* xt = ws + WS_XT;
      xt[b0 * 128 + d0] = a00 + ipb[d0];
      xt[b0 * 128 + d0 + 1] = a01 + ipb[d0 + 1];
      xt[(b0 + 1) * 128 + d0] = a10 + ipb[d0];
      xt[(b0 + 1) * 128 + d0 + 1] = a11 + ipb[d0 + 1];
    }
  }
}

// K2: one block per d. At[d,:] via coalesced EJT reads, colsum from staged
// NS column, then register-resident step1+step2 for all 32 b.
__global__ __launch_bounds__(256) void k2_brain(const float* __restrict__ ns,
                                                float* __restrict__ ws) {
  __shared__ float nscol[128], xts[32], at2[2][128], Atf[128];
  __shared__ float csum_s;
  int tid = threadIdx.x, d = blockIdx.x;
  if (tid < 128) nscol[tid] = ns[tid * 128 + d];
  else if (tid < 160) xts[tid - 128] = (ws + WS_XT)[(tid - 128) * 128 + d];
  __syncthreads();
  {
    int i = tid & 127, h = tid >> 7;
    const float* EJTp = ws + WS_EJT + h * 64 * 128 + i;
    const float* nsr = &nscol[h * 64];
    float a = 0.f;
#pragma unroll 8
    for (int n = 0; n < 64; ++n) a += EJTp[n * 128] * nsr[n];
    at2[h][i] = a;
  }
  if (tid < 64) {
    float cl = nscol[tid] + nscol[tid + 64];
    cl = wave_reduce64(cl);
    if (tid == 0) csum_s = cl;
  }
  __syncthreads();
  if (tid < 128) Atf[tid] = at2[0][tid] + at2[1][tid];
  __syncthreads();
  int wv = tid >> 6, l = tid & 63;
  float a0 = Atf[l], a1 = Atf[l + 64];
  float e0 = (ws + WS_E)[l], e1 = (ws + WS_E)[l + 64];
  float q0 = (ws + WS_EJ127)[l], q1 = (ws + WS_EJ127)[l + 64];
  float csum = csum_s;
  bool z0 = (l == d), z1 = (l + 64 == d);
  float* obd = ws + WS_OBD;
#pragma unroll
  for (int bb = 0; bb < 8; ++bb) {
    int b = wv * 8 + bb;
    float t = xts[b];
    float s0s = csum + 128.f * t;
    float v0 = s0s * (a0 + t * e0);
    float v1 = s0s * (a1 + t * e1);
    v0 = z0 ? 0.f : fmaxf(v0, 0.f);  // step-1 mask + relu
    v1 = z1 ? 0.f : fmaxf(v1, 0.f);
    float sig = wave_reduce64(v0 + v1);
    float y = wave_reduce64(q0 * v0 + q1 * v1);
    if (l == 0) {
      float m2 = sig * y;
      if (d == 127) m2 = 0.f;  // step-2 mask (i=127)
      obd[b * 128 + d] = fmaxf(m2, 0.f);
    }
  }
}

// K3: blocks 0..143: recreation tile 32 f x 32 b; block 144: scores
__global__ __launch_bounds__(256) void k3_proj(const float* __restrict__ rw,
                                               const float* __restrict__ rb,
                                               const float* __restrict__ sw,
                                               const float* __restrict__ sb,
                                               const float* __restrict__ ws,
                                               float* __restrict__ out) {
  const float* obd = ws + WS_OBD;
  int tid = threadIdx.x;
  int blk = blockIdx.x;
  if (blk < 144) {
    __shared__ __align__(16) float rwlds[32 * 136];
    __shared__ float obdT[128 * 33];
    int f0 = blk * 32;
    const float4* rw4 = (const float4*)rw;
#pragma unroll
    for (int it = 0; it < 4; ++it) {
      int q = tid + 256 * it;
      int f = q >> 5, n4 = q & 31;
      *(float4*)&rwlds[f * 136 + n4 * 4] = rw4[f0 * 32 + q];
    }
#pragma unroll
    for (int it = 0; it < 16; ++it) {
      int q = tid + 256 * it;
      int b = q >> 7, dd = q & 127;
      obdT[dd * 33 + b] = obd[q];
    }
    __syncthreads();
    int f = tid >> 3, bg = tid & 7;
    float acc[4] = {0.f, 0.f, 0.f, 0.f};
#pragma unroll 4
    for (int d = 0; d < 128; ++d) {
      float w = rwlds[f * 136 + d];
#pragma unroll
      for (int k = 0; k < 4; ++k) acc[k] += w * obdT[d * 33 + bg * 4 + k];
    }
    float bias = rb[f0 + f];
#pragma unroll
    for (int k = 0; k < 4; ++k) out[(bg * 4 + k) * 4608 + f0 + f] = acc[k] + bias;
  } else {
    int b = tid >> 3, l8 = tid & 7;
    float acc = 0.f;
    for (int d = l8; d < 128; d += 8) acc += obd[b * 128 + d] * sw[d];
    acc += __shfl_xor(acc, 1);
    acc += __shfl_xor(acc, 2);
    acc += __shfl_xor(acc, 4);
    if (l8 == 0) out[147456 + b] = acc + sb[0];
  }
}

extern "C" void kernel_launch(void* const* d_in, const int* in_sizes, int n_in,
                              void* d_out, int out_size, void* d_ws, size_t ws_size,
                              hipStream_t stream) {
  const float* x   = (const float*)d_in[0];   // (32, 4608)
  const float* ipw = (const float*)d_in[1];   // (128, 4608)
  const float* ipb = (const float*)d_in[2];   // (128,)
  const float* ns  = (const float*)d_in[3];   // (128, 128)
  const float* ev  = (const float*)d_in[4];   // (128, 128, 128)
  const float* rw  = (const float*)d_in[5];   // (4608, 128)
  const float* rb  = (const float*)d_in[6];   // (4608,)
  const float* sw  = (const float*)d_in[7];   // (1, 128)
  const float* sb  = (const float*)d_in[8];   // (1,)
  float* out = (float*)d_out;                 // 147456 recreation + 32 scores
  float* ws = (float*)d_ws;                   // needs >= 24832 floats (~99 KB)

  k1_pre<<<384, 256, 0, stream>>>(ev, x, ipw, ipb, ws);
  k2_brain<<<128, 256, 0, stream>>>(ns, ws);
  k3_proj<<<145, 256, 0, stream>>>(rw, rb, sw, sb, ws, out);
}